// Round 2
// baseline (16776.865 us; speedup 1.0000x reference)
//
#include <hip/hip_runtime.h>
#include <hip/hip_bf16.h>
#include <cstdint>
#include <cstddef>

// T=256, B=64, IN=2048, H=1024, L=3, D=2
// Phased: 16 timesteps/phase, 16 phases/layer.
// GX: [2048][3072] fp32 (fwd local rows 0..1023 = cols 0..3071 of fwd gates;
//     bwd local rows 1024..2047 = cols of bwd gates). 24 MiB.
// Recurrence: ONE kernel per phase (16 steps), hand-rolled grid barrier
// (graph-capture-safe; hipLaunchCooperativeKernel is NOT capturable).

typedef short short8 __attribute__((ext_vector_type(8)));
typedef float f32x4 __attribute__((ext_vector_type(4)));

__device__ __forceinline__ void async16(const void* g, void* l) {
  __builtin_amdgcn_global_load_lds(
      (const __attribute__((address_space(1))) unsigned int*)g,
      (__attribute__((address_space(3))) unsigned int*)l,
      16, 0, 0);
}

// ---------------- fp32 -> bf16 convert (grid-stride) ----------------
__global__ void f2b(const float* __restrict__ src, __hip_bfloat16* __restrict__ dst, int n) {
  int i = blockIdx.x * blockDim.x + threadIdx.x;
  int stride = gridDim.x * blockDim.x;
  for (; i < n; i += stride) dst[i] = __float2bfloat16(src[i]);
}

__global__ void zerou(unsigned* p) { if (threadIdx.x == 0) *p = 0u; }

// ---------------- bf16 GEMM (phased, halved): C[2048][3072] ----------------
__global__ __launch_bounds__(256) void gemm_bias_bt(
    const __hip_bfloat16* __restrict__ A,
    const __hip_bfloat16* __restrict__ Bw,
    const float* __restrict__ bias,
    float* __restrict__ C,
    int rowBase0, int rowBase1) {
  __shared__ short As[128 * 32];
  __shared__ short Bs[128 * 32];
  const int tid = threadIdx.x;
  const int lane = tid & 63;
  const int wid = tid >> 6;
  const int m0 = blockIdx.x * 128;
  const int n0 = blockIdx.y * 128;
  const int grow = (m0 < 1024) ? (rowBase0 + m0) : (rowBase1 + (m0 - 1024));
  const int cb = (m0 < 1024) ? 0 : 3072;
  const int wm = wid & 1, wn = wid >> 1;

  f32x4 acc[4][4] = {};

  const short* Ag = (const short*)A;
  const short* Bg = (const short*)Bw + (size_t)cb * 2048;
  const int srow = wid * 16 + (lane >> 2);
  const int sk = (lane & 3) * 8;

  for (int kb = 0; kb < 2048; kb += 32) {
    async16(Ag + (size_t)(grow + srow) * 2048 + kb + sk, &As[wid * 512]);
    async16(Ag + (size_t)(grow + srow + 64) * 2048 + kb + sk, &As[wid * 512 + 2048]);
    async16(Bg + (size_t)(n0 + srow) * 2048 + kb + sk, &Bs[wid * 512]);
    async16(Bg + (size_t)(n0 + srow + 64) * 2048 + kb + sk, &Bs[wid * 512 + 2048]);
    __syncthreads();

    const int q = (lane >> 4) * 8;
    const int rl = lane & 15;
    short8 a[4], b[4];
#pragma unroll
    for (int i = 0; i < 4; i++) a[i] = *(const short8*)&As[(wm * 64 + i * 16 + rl) * 32 + q];
#pragma unroll
    for (int j = 0; j < 4; j++) b[j] = *(const short8*)&Bs[(wn * 64 + j * 16 + rl) * 32 + q];
#pragma unroll
    for (int i = 0; i < 4; i++)
#pragma unroll
      for (int j = 0; j < 4; j++)
        acc[i][j] = __builtin_amdgcn_mfma_f32_16x16x32_bf16(a[i], b[j], acc[i][j], 0, 0, 0);
    __syncthreads();
  }

  const int rl = lane & 15;
  const int rq = lane >> 4;
#pragma unroll
  for (int i = 0; i < 4; i++) {
#pragma unroll
    for (int j = 0; j < 4; j++) {
      int col = n0 + wn * 64 + j * 16 + rl;
      float bv = bias[cb + col];
#pragma unroll
      for (int r = 0; r < 4; r++) {
        int row = m0 + wm * 64 + i * 16 + rq * 4 + r;
        C[(size_t)row * 3072 + col] = acc[i][j][r] + bv;
      }
    }
  }
}

// ---------------- device-scope grid barrier (graph-capture-safe) ----------------
// Monotone epoch counter: each block's thread 0 arrives (release, agent scope)
// and spins until count >= target (acquire, agent scope). Safe because grid=256
// blocks with __launch_bounds__(512,2) => >=1 block/CU => all blocks co-resident.
// Bounded spin turns any residual hazard into a correctness failure, not a hang.
__device__ __forceinline__ void grid_sync(unsigned* bar, unsigned target) {
  __syncthreads();
  if (threadIdx.x == 0) {
    __hip_atomic_fetch_add(bar, 1u, __ATOMIC_RELEASE, __HIP_MEMORY_SCOPE_AGENT);
    int guard = 1 << 18;
    while (__hip_atomic_load(bar, __ATOMIC_ACQUIRE, __HIP_MEMORY_SCOPE_AGENT) < target &&
           --guard) {
      __builtin_amdgcn_s_sleep(1);
    }
    __builtin_amdgcn_fence(__ATOMIC_ACQUIRE, "agent");
  }
  __syncthreads();
}

// ---------------- phase kernel: 16 GRU steps, 1 launch ----------------
// Grid 256 blocks x 512 thr. block = (mh:2)*128 + (d:2)*64 + (ct:64).
// 8 waves = (kq:4 K-quarters) x (mts:2 16-row batch tiles). Block output:
// 32 batch rows x 16 cols x 3 gates. W_hh slice register-resident (96 VGPR/lane,
// loaded once per launch). fp32 h carried in a register per lane across steps.
__global__ __launch_bounds__(512, 2) void gru_phase(
    const __hip_bfloat16* __restrict__ Whhb,  // [6144][1024] bf16
    const float* __restrict__ bhh,            // [6144]
    const float* __restrict__ GX,             // [2048][3072]
    __hip_bfloat16* __restrict__ HB,          // [2][2][64][1024] bf16 double buffer
    float* __restrict__ HF,                   // [2][64][1024] fp32 (phase boundary)
    const float* __restrict__ hfin,           // fp32 h at phase start (h0 or HF)
    __hip_bfloat16* __restrict__ Y,           // [256][64][2048]
    float* __restrict__ outF,                 // [2][64][1024] (final h_n slice)
    unsigned* __restrict__ bar,
    int ph, int writeY, int syncbase) {
  __shared__ float P[2][4][3][16][17];

  const int bid = blockIdx.x;
  const int mh = bid >> 7;
  const int d = (bid >> 6) & 1;
  const int ct = bid & 63;
  const int lane = threadIdx.x & 63;
  const int wid = threadIdx.x >> 6;
  const int kq = wid >> 1;   // K-quarter: [kq*256, kq*256+256)
  const int mts = wid & 1;
  const int mt = mh * 2 + mts;
  const int rl = lane & 15;
  const int rq = lane >> 4;

  // ---- register-resident weights: 16 cols x 256 K x 3 gates = 24 short8 ----
  const short* wbase = (const short*)Whhb + (size_t)(d * 3072 + ct * 16 + rl) * 1024 + kq * 256 + rq * 8;
  short8 wB[3][8];
#pragma unroll
  for (int g = 0; g < 3; ++g)
#pragma unroll
    for (int ki = 0; ki < 8; ++ki)
      wB[g][ki] = *(const short8*)&wbase[g * 1048576 + ki * 32];

  // ---- per-lane epilogue assignment: (b, c) fixed for all 16 steps ----
  const int c = ct * 16 + rl;
  const float bR = bhh[d * 3072 + c];
  const float bZ = bhh[d * 3072 + 1024 + c];
  const float bN = bhh[d * 3072 + 2048 + c];
  const int b = mt * 16 + kq * 4 + rq;
  const int hoff = d * 65536 + b * 1024 + c;
  float hp = hfin[hoff];  // fp32 h carried in-register across steps

  const int aoff = d * 65536 + (mt * 16 + rl) * 1024 + kq * 256 + rq * 8;

#pragma unroll 1
  for (int u = 0; u < 16; ++u) {
    if (u) grid_sync(bar, (unsigned)(syncbase + u) * 256u);
    const int t = ph * 16 + u;

    // GX loads (h-independent) issue early
    const int gxBase = d ? (1024 + (15 - u) * 64) : (u * 64);
    const float* gp = GX + (size_t)(gxBase + b) * 3072 + c;
    const float gxr = gp[0];
    const float gxz = gp[1024];
    const float gxn = gp[2048];

    // A-operand: bf16 h from the (t&1) buffer
    const short* hrow = (const short*)HB + (t & 1) * 131072 + aoff;
    short8 av[8];
#pragma unroll
    for (int ki = 0; ki < 8; ++ki) av[ki] = *(const short8*)&hrow[ki * 32];

    f32x4 aR = {}, aZ = {}, aN = {};
#pragma unroll
    for (int ki = 0; ki < 8; ++ki) {
      aR = __builtin_amdgcn_mfma_f32_16x16x32_bf16(av[ki], wB[0][ki], aR, 0, 0, 0);
      aZ = __builtin_amdgcn_mfma_f32_16x16x32_bf16(av[ki], wB[1][ki], aZ, 0, 0, 0);
      aN = __builtin_amdgcn_mfma_f32_16x16x32_bf16(av[ki], wB[2][ki], aN, 0, 0, 0);
    }

    // 4-way K reduce through LDS
#pragma unroll
    for (int r = 0; r < 4; ++r) {
      P[mts][kq][0][rq * 4 + r][rl] = aR[r];
      P[mts][kq][1][rq * 4 + r][rl] = aZ[r];
      P[mts][kq][2][rq * 4 + r][rl] = aN[r];
    }
    __syncthreads();

    const int row = kq * 4 + rq;
    const float ghR = P[mts][0][0][row][rl] + P[mts][1][0][row][rl] +
                      P[mts][2][0][row][rl] + P[mts][3][0][row][rl] + bR;
    const float ghZ = P[mts][0][1][row][rl] + P[mts][1][1][row][rl] +
                      P[mts][2][1][row][rl] + P[mts][3][1][row][rl] + bZ;
    const float ghN = P[mts][0][2][row][rl] + P[mts][1][2][row][rl] +
                      P[mts][2][2][row][rl] + P[mts][3][2][row][rl] + bN;

    const float rg = 1.f / (1.f + __expf(-(gxr + ghR)));
    const float zg = 1.f / (1.f + __expf(-(gxz + ghZ)));
    const float nv = gxn + rg * ghN;
    const float ax = fabsf(nv);
    const float e = __expf(-2.f * ax);
    float th = (1.f - e) / (1.f + e);
    th = copysignf(th, nv);
    const float hn = th + zg * (hp - th);
    hp = hn;

    HB[((t + 1) & 1) * 131072 + hoff] = __float2bfloat16(hn);
    if (writeY) Y[(size_t)((d ? 255 - t : t) * 64 + b) * 2048 + d * 1024 + c] = __float2bfloat16(hn);
    if (u == 15) {
      HF[hoff] = hn;                   // fp32 h for next phase's init
      if (t == 255) outF[hoff] = hn;   // final h_n
    }
  }
}

// ---------------- launch ----------------
extern "C" void kernel_launch(void* const* d_in, const int* in_sizes, int n_in,
                              void* d_out, int out_size, void* d_ws, size_t ws_size,
                              hipStream_t stream) {
  (void)in_sizes; (void)n_in; (void)out_size; (void)ws_size;
  const float* x    = (const float*)d_in[0];
  const float* h0   = (const float*)d_in[1];
  const float* w_ih = (const float*)d_in[2];
  const float* w_hh = (const float*)d_in[3];
  const float* b_ih = (const float*)d_in[4];
  const float* b_hh = (const float*)d_in[5];
  float* out = (float*)d_out;

  char* p = (char*)d_ws;
  __hip_bfloat16* SEQA = (__hip_bfloat16*)p; p += (size_t)16384 * 2048 * 2;   // 64 MiB
  __hip_bfloat16* SEQB = (__hip_bfloat16*)p; p += (size_t)16384 * 2048 * 2;   // 64 MiB
  float* GX            = (float*)p;          p += (size_t)2048 * 3072 * 4;    // 24 MiB
  __hip_bfloat16* Wihb = (__hip_bfloat16*)p; p += (size_t)6144 * 2048 * 2;    // 24 MiB
  __hip_bfloat16* Whhb = (__hip_bfloat16*)p; p += (size_t)6144 * 1024 * 2;    // 12 MiB
  __hip_bfloat16* HB   = (__hip_bfloat16*)p; p += (size_t)2 * 131072 * 2;     // 512 KiB
  float* HF            = (float*)p;          p += (size_t)2 * 131072 * 4;     // 1 MiB
  unsigned* BAR        = (unsigned*)p;       p += 256;

  zerou<<<1, 64, 0, stream>>>(BAR);
  f2b<<<2048, 256, 0, stream>>>(x, SEQA, 16384 * 2048);

  int syncbase = 0;
  for (int l = 0; l < 3; ++l) {
    const __hip_bfloat16* In = (l & 1) ? SEQB : SEQA;
    __hip_bfloat16* Yout = (l & 1) ? SEQA : SEQB;   // unused for l==2
    const int writeY = (l < 2) ? 1 : 0;

    f2b<<<2048, 256, 0, stream>>>(w_ih + (size_t)l * 6144 * 2048, Wihb, 6144 * 2048);
    f2b<<<2048, 256, 0, stream>>>(w_hh + (size_t)l * 6144 * 1024, Whhb, 6144 * 1024);
    f2b<<<64, 256, 0, stream>>>(h0 + (size_t)l * 131072, HB, 131072);

    for (int ph = 0; ph < 16; ++ph) {
      const int rowBase0 = ph * 1024;            // fwd t in [16p, 16p+16)
      const int rowBase1 = 15360 - ph * 1024;    // bwd tau in [240-16p, 256-16p)
      gemm_bias_bt<<<dim3(16, 24), 256, 0, stream>>>(
          In, Wihb, b_ih + l * 6144, GX, rowBase0, rowBase1);

      const float* hfin = (ph == 0) ? (h0 + (size_t)l * 131072) : HF;
      gru_phase<<<256, 512, 0, stream>>>(
          Whhb, b_hh + l * 6144, GX, HB, HF, hfin, Yout,
          out + (size_t)l * 131072, BAR, ph, writeY, syncbase);
      syncbase += 15;   // 15 grid syncs per phase launch
    }
  }
}

// Round 3
// 12252.313 us; speedup vs baseline: 1.3693x; 1.3693x over previous
//
#include <hip/hip_runtime.h>
#include <hip/hip_bf16.h>
#include <cstdint>
#include <cstddef>

// T=256, B=64, IN=2048, H=1024, L=3, D=2
// Phased: 16 timesteps/phase, 16 phases/layer.
// GX: [2048][3072] fp32 (fwd local rows 0..1023 = cols 0..3071 of fwd gates;
//     bwd local rows 1024..2047 = cols of bwd gates). 24 MiB.
// Recurrence: ONE kernel per phase (16 steps), hand-rolled grid barrier
// (graph-capture-safe). Round-3 fixes: weights laundered into VGPRs (compiler
// was re-loading 50 MB/step due to restrict-const remat), relaxed-poll barrier
// (acquire-per-poll emitted an L2 invalidate per spin iteration), per-direction
// barriers (128 participants each).

typedef short short8 __attribute__((ext_vector_type(8)));
typedef float f32x4 __attribute__((ext_vector_type(4)));

__device__ __forceinline__ void async16(const void* g, void* l) {
  __builtin_amdgcn_global_load_lds(
      (const __attribute__((address_space(1))) unsigned int*)g,
      (__attribute__((address_space(3))) unsigned int*)l,
      16, 0, 0);
}

// launder: make a loaded value opaque so the compiler cannot re-materialize it
// from memory (legal for restrict-const loads even across memory clobbers).
__device__ __forceinline__ void keep8(short8& v) { asm volatile("" : "+v"(v)); }
__device__ __forceinline__ void keepf(float& v) { asm volatile("" : "+v"(v)); }

// ---------------- fp32 -> bf16 convert (grid-stride) ----------------
__global__ void f2b(const float* __restrict__ src, __hip_bfloat16* __restrict__ dst, int n) {
  int i = blockIdx.x * blockDim.x + threadIdx.x;
  int stride = gridDim.x * blockDim.x;
  for (; i < n; i += stride) dst[i] = __float2bfloat16(src[i]);
}

__global__ void zerou(unsigned* p, int n) {
  int i = threadIdx.x;
  if (i < n) p[i] = 0u;
}

// ---------------- bf16 GEMM (phased, halved): C[2048][3072] ----------------
__global__ __launch_bounds__(256) void gemm_bias_bt(
    const __hip_bfloat16* __restrict__ A,
    const __hip_bfloat16* __restrict__ Bw,
    const float* __restrict__ bias,
    float* __restrict__ C,
    int rowBase0, int rowBase1) {
  __shared__ short As[128 * 32];
  __shared__ short Bs[128 * 32];
  const int tid = threadIdx.x;
  const int lane = tid & 63;
  const int wid = tid >> 6;
  const int m0 = blockIdx.x * 128;
  const int n0 = blockIdx.y * 128;
  const int grow = (m0 < 1024) ? (rowBase0 + m0) : (rowBase1 + (m0 - 1024));
  const int cb = (m0 < 1024) ? 0 : 3072;
  const int wm = wid & 1, wn = wid >> 1;

  f32x4 acc[4][4] = {};

  const short* Ag = (const short*)A;
  const short* Bg = (const short*)Bw + (size_t)cb * 2048;
  const int srow = wid * 16 + (lane >> 2);
  const int sk = (lane & 3) * 8;

  for (int kb = 0; kb < 2048; kb += 32) {
    async16(Ag + (size_t)(grow + srow) * 2048 + kb + sk, &As[wid * 512]);
    async16(Ag + (size_t)(grow + srow + 64) * 2048 + kb + sk, &As[wid * 512 + 2048]);
    async16(Bg + (size_t)(n0 + srow) * 2048 + kb + sk, &Bs[wid * 512]);
    async16(Bg + (size_t)(n0 + srow + 64) * 2048 + kb + sk, &Bs[wid * 512 + 2048]);
    __syncthreads();

    const int q = (lane >> 4) * 8;
    const int rl = lane & 15;
    short8 a[4], b[4];
#pragma unroll
    for (int i = 0; i < 4; i++) a[i] = *(const short8*)&As[(wm * 64 + i * 16 + rl) * 32 + q];
#pragma unroll
    for (int j = 0; j < 4; j++) b[j] = *(const short8*)&Bs[(wn * 64 + j * 16 + rl) * 32 + q];
#pragma unroll
    for (int i = 0; i < 4; i++)
#pragma unroll
      for (int j = 0; j < 4; j++)
        acc[i][j] = __builtin_amdgcn_mfma_f32_16x16x32_bf16(a[i], b[j], acc[i][j], 0, 0, 0);
    __syncthreads();
  }

  const int rl = lane & 15;
  const int rq = lane >> 4;
#pragma unroll
  for (int i = 0; i < 4; i++) {
#pragma unroll
    for (int j = 0; j < 4; j++) {
      int col = n0 + wn * 64 + j * 16 + rl;
      float bv = bias[cb + col];
#pragma unroll
      for (int r = 0; r < 4; r++) {
        int row = m0 + wm * 64 + i * 16 + rq * 4 + r;
        C[(size_t)row * 3072 + col] = acc[i][j][r] + bv;
      }
    }
  }
}

// ---------------- device-scope grid barrier (graph-capture-safe) ----------------
// Monotone epoch counter. RELAXED polling (one acquire fence at exit — acquire
// per-poll would emit an L2 invalidate per spin iteration). Safe: grid=256
// blocks, 1 block/CU on 256 CUs => all blocks co-resident. Bounded spin turns
// any residual hazard into a correctness failure, not a hang.
__device__ __forceinline__ void grid_sync(unsigned* bar, unsigned target) {
  __syncthreads();
  if (threadIdx.x == 0) {
    __hip_atomic_fetch_add(bar, 1u, __ATOMIC_RELEASE, __HIP_MEMORY_SCOPE_AGENT);
    int guard = 1 << 18;
    while (__hip_atomic_load(bar, __ATOMIC_RELAXED, __HIP_MEMORY_SCOPE_AGENT) < target &&
           --guard) {
      __builtin_amdgcn_s_sleep(2);
    }
    __builtin_amdgcn_fence(__ATOMIC_ACQUIRE, "agent");
  }
  __syncthreads();
}

// ---------------- phase kernel: 16 GRU steps, 1 launch ----------------
// Grid 256 blocks x 512 thr. block = (mh:2)*128 + (d:2)*64 + (ct:64).
// 8 waves = (kq:4 K-quarters) x (mts:2 16-row batch tiles). Block output:
// 32 batch rows x 16 cols x 3 gates. W_hh slice register-resident (96 VGPR/lane,
// loaded once per launch, laundered so the compiler can't re-load). fp32 h
// carried in a register per lane across steps. Per-direction barrier.
__global__ __launch_bounds__(512, 2) void gru_phase(
    const __hip_bfloat16* __restrict__ Whhb,  // [6144][1024] bf16
    const float* __restrict__ bhh,            // [6144]
    const float* __restrict__ GX,             // [2048][3072]
    __hip_bfloat16* __restrict__ HB,          // [2][2][64][1024] bf16 double buffer
    float* __restrict__ HF,                   // [2][64][1024] fp32 (phase boundary)
    const float* __restrict__ hfin,           // fp32 h at phase start (h0 or HF)
    __hip_bfloat16* __restrict__ Y,           // [256][64][2048]
    float* __restrict__ outF,                 // [2][64][1024] (final h_n slice)
    unsigned* __restrict__ bar,               // [2 counters, 256B apart]
    int ph, int writeY, int syncbase) {
  __shared__ float P[2][4][3][16][17];

  const int bid = blockIdx.x;
  const int mh = bid >> 7;
  const int d = (bid >> 6) & 1;
  const int ct = bid & 63;
  const int lane = threadIdx.x & 63;
  const int wid = threadIdx.x >> 6;
  const int kq = wid >> 1;   // K-quarter: [kq*256, kq*256+256)
  const int mts = wid & 1;
  const int mt = mh * 2 + mts;
  const int rl = lane & 15;
  const int rq = lane >> 4;

  unsigned* mybar = bar + d * 64;  // per-direction counter, 256B apart

  // ---- register-resident weights: 16 cols x 256 K x 3 gates = 24 short8 ----
  const short* wbase = (const short*)Whhb + (size_t)(d * 3072 + ct * 16 + rl) * 1024 + kq * 256 + rq * 8;
  short8 wB[3][8];
#pragma unroll
  for (int g = 0; g < 3; ++g)
#pragma unroll
    for (int ki = 0; ki < 8; ++ki)
      wB[g][ki] = *(const short8*)&wbase[g * 1048576 + ki * 32];
#pragma unroll
  for (int g = 0; g < 3; ++g)
#pragma unroll
    for (int ki = 0; ki < 8; ++ki)
      keep8(wB[g][ki]);   // pin in VGPRs: forbid remat-from-memory across fences

  // ---- per-lane epilogue assignment: (b, c) fixed for all 16 steps ----
  const int c = ct * 16 + rl;
  float bR = bhh[d * 3072 + c];
  float bZ = bhh[d * 3072 + 1024 + c];
  float bN = bhh[d * 3072 + 2048 + c];
  keepf(bR); keepf(bZ); keepf(bN);
  const int b = mt * 16 + kq * 4 + rq;
  const int hoff = d * 65536 + b * 1024 + c;
  float hp = hfin[hoff];  // fp32 h carried in-register across steps

  const int aoff = d * 65536 + (mt * 16 + rl) * 1024 + kq * 256 + rq * 8;

#pragma unroll 1
  for (int u = 0; u < 16; ++u) {
    if (u) grid_sync(mybar, (unsigned)(syncbase + u) * 128u);
    const int t = ph * 16 + u;

    // GX loads (h-independent) issue early
    const int gxBase = d ? (1024 + (15 - u) * 64) : (u * 64);
    const float* gp = GX + (size_t)(gxBase + b) * 3072 + c;
    const float gxr = gp[0];
    const float gxz = gp[1024];
    const float gxn = gp[2048];

    // A-operand: bf16 h from the (t&1) buffer
    const short* hrow = (const short*)HB + (t & 1) * 131072 + aoff;
    short8 av[8];
#pragma unroll
    for (int ki = 0; ki < 8; ++ki) av[ki] = *(const short8*)&hrow[ki * 32];

    f32x4 aR = {}, aZ = {}, aN = {};
#pragma unroll
    for (int ki = 0; ki < 8; ++ki) {
      aR = __builtin_amdgcn_mfma_f32_16x16x32_bf16(av[ki], wB[0][ki], aR, 0, 0, 0);
      aZ = __builtin_amdgcn_mfma_f32_16x16x32_bf16(av[ki], wB[1][ki], aZ, 0, 0, 0);
      aN = __builtin_amdgcn_mfma_f32_16x16x32_bf16(av[ki], wB[2][ki], aN, 0, 0, 0);
    }

    // 4-way K reduce through LDS
#pragma unroll
    for (int r = 0; r < 4; ++r) {
      P[mts][kq][0][rq * 4 + r][rl] = aR[r];
      P[mts][kq][1][rq * 4 + r][rl] = aZ[r];
      P[mts][kq][2][rq * 4 + r][rl] = aN[r];
    }
    __syncthreads();

    const int row = kq * 4 + rq;
    const float ghR = P[mts][0][0][row][rl] + P[mts][1][0][row][rl] +
                      P[mts][2][0][row][rl] + P[mts][3][0][row][rl] + bR;
    const float ghZ = P[mts][0][1][row][rl] + P[mts][1][1][row][rl] +
                      P[mts][2][1][row][rl] + P[mts][3][1][row][rl] + bZ;
    const float ghN = P[mts][0][2][row][rl] + P[mts][1][2][row][rl] +
                      P[mts][2][2][row][rl] + P[mts][3][2][row][rl] + bN;

    const float rg = 1.f / (1.f + __expf(-(gxr + ghR)));
    const float zg = 1.f / (1.f + __expf(-(gxz + ghZ)));
    const float nv = gxn + rg * ghN;
    const float ax = fabsf(nv);
    const float e = __expf(-2.f * ax);
    float th = (1.f - e) / (1.f + e);
    th = copysignf(th, nv);
    const float hn = th + zg * (hp - th);
    hp = hn;

    HB[((t + 1) & 1) * 131072 + hoff] = __float2bfloat16(hn);
    if (writeY) Y[(size_t)((d ? 255 - t : t) * 64 + b) * 2048 + d * 1024 + c] = __float2bfloat16(hn);
    if (u == 15) {
      HF[hoff] = hn;                   // fp32 h for next phase's init
      if (t == 255) outF[hoff] = hn;   // final h_n
    }
  }
}

// ---------------- launch ----------------
extern "C" void kernel_launch(void* const* d_in, const int* in_sizes, int n_in,
                              void* d_out, int out_size, void* d_ws, size_t ws_size,
                              hipStream_t stream) {
  (void)in_sizes; (void)n_in; (void)out_size; (void)ws_size;
  const float* x    = (const float*)d_in[0];
  const float* h0   = (const float*)d_in[1];
  const float* w_ih = (const float*)d_in[2];
  const float* w_hh = (const float*)d_in[3];
  const float* b_ih = (const float*)d_in[4];
  const float* b_hh = (const float*)d_in[5];
  float* out = (float*)d_out;

  char* p = (char*)d_ws;
  __hip_bfloat16* SEQA = (__hip_bfloat16*)p; p += (size_t)16384 * 2048 * 2;   // 64 MiB
  __hip_bfloat16* SEQB = (__hip_bfloat16*)p; p += (size_t)16384 * 2048 * 2;   // 64 MiB
  float* GX            = (float*)p;          p += (size_t)2048 * 3072 * 4;    // 24 MiB
  __hip_bfloat16* Wihb = (__hip_bfloat16*)p; p += (size_t)6144 * 2048 * 2;    // 24 MiB
  __hip_bfloat16* Whhb = (__hip_bfloat16*)p; p += (size_t)6144 * 1024 * 2;    // 12 MiB
  __hip_bfloat16* HB   = (__hip_bfloat16*)p; p += (size_t)2 * 131072 * 2;     // 512 KiB
  float* HF            = (float*)p;          p += (size_t)2 * 131072 * 4;     // 1 MiB
  unsigned* BAR        = (unsigned*)p;       p += 1024;

  zerou<<<1, 256, 0, stream>>>(BAR, 128);
  f2b<<<2048, 256, 0, stream>>>(x, SEQA, 16384 * 2048);

  int syncbase = 0;
  for (int l = 0; l < 3; ++l) {
    const __hip_bfloat16* In = (l & 1) ? SEQB : SEQA;
    __hip_bfloat16* Yout = (l & 1) ? SEQA : SEQB;   // unused for l==2
    const int writeY = (l < 2) ? 1 : 0;

    f2b<<<2048, 256, 0, stream>>>(w_ih + (size_t)l * 6144 * 2048, Wihb, 6144 * 2048);
    f2b<<<2048, 256, 0, stream>>>(w_hh + (size_t)l * 6144 * 1024, Whhb, 6144 * 1024);
    f2b<<<64, 256, 0, stream>>>(h0 + (size_t)l * 131072, HB, 131072);

    for (int ph = 0; ph < 16; ++ph) {
      const int rowBase0 = ph * 1024;            // fwd t in [16p, 16p+16)
      const int rowBase1 = 15360 - ph * 1024;    // bwd tau in [240-16p, 256-16p)
      gemm_bias_bt<<<dim3(16, 24), 256, 0, stream>>>(
          In, Wihb, b_ih + l * 6144, GX, rowBase0, rowBase1);

      const float* hfin = (ph == 0) ? (h0 + (size_t)l * 131072) : HF;
      gru_phase<<<256, 512, 0, stream>>>(
          Whhb, b_hh + l * 6144, GX, HB, HF, hfin, Yout,
          out + (size_t)l * 131072, BAR, ph, writeY, syncbase);
      syncbase += 15;   // 15 grid syncs per phase launch
    }
  }
}

// Round 4
// 6684.359 us; speedup vs baseline: 2.5099x; 1.8330x over previous
//
#include <hip/hip_runtime.h>
#include <hip/hip_bf16.h>
#include <cstdint>
#include <cstddef>

// T=256, B=64, IN=2048, H=1024, L=3, D=2
// Phased: 16 timesteps/phase, 16 phases/layer.
// GX: [2048][3072] fp32. Recurrence: ONE kernel per phase (16 steps),
// fence-free grid barrier: h exchanged via sc0/sc1 (MALL-coherent) accesses,
// barrier is relaxed-atomic + relaxed-poll with NO acquire/release fences
// (round 3's agent fences invalidated L2 every step -> ~24 MB/step refills).

typedef short short8 __attribute__((ext_vector_type(8)));
typedef float f32x4 __attribute__((ext_vector_type(4)));

__device__ __forceinline__ void async16(const void* g, void* l) {
  __builtin_amdgcn_global_load_lds(
      (const __attribute__((address_space(1))) unsigned int*)g,
      (__attribute__((address_space(3))) unsigned int*)l,
      16, 0, 0);
}

// launder: make a loaded value opaque so the compiler cannot re-materialize it
// from memory across barrier clobbers.
__device__ __forceinline__ void keep8(short8& v) { asm volatile("" : "+v"(v)); }
__device__ __forceinline__ void keepf(float& v) { asm volatile("" : "+v"(v)); }

// 8x16B coherent loads (bypass L1/L2, read MALL). One vmcnt(0) for the batch.
__device__ __forceinline__ void load_h8_coherent(const short* p, short8 av[8]) {
  asm volatile(
      "global_load_dwordx4 %0, %8, off sc0 sc1\n\t"
      "global_load_dwordx4 %1, %8, off offset:64 sc0 sc1\n\t"
      "global_load_dwordx4 %2, %8, off offset:128 sc0 sc1\n\t"
      "global_load_dwordx4 %3, %8, off offset:192 sc0 sc1\n\t"
      "global_load_dwordx4 %4, %8, off offset:256 sc0 sc1\n\t"
      "global_load_dwordx4 %5, %8, off offset:320 sc0 sc1\n\t"
      "global_load_dwordx4 %6, %8, off offset:384 sc0 sc1\n\t"
      "global_load_dwordx4 %7, %8, off offset:448 sc0 sc1\n\t"
      "s_waitcnt vmcnt(0)"
      : "=&v"(av[0]), "=&v"(av[1]), "=&v"(av[2]), "=&v"(av[3]),
        "=&v"(av[4]), "=&v"(av[5]), "=&v"(av[6]), "=&v"(av[7])
      : "v"(p)
      : "memory");
}

// 2-byte coherent store (write-through to MALL).
__device__ __forceinline__ void store_h_coherent(void* p, unsigned int v) {
  asm volatile("global_store_short %0, %1, off sc0 sc1" :: "v"(p), "v"(v) : "memory");
}

// ---------------- fp32 -> bf16 convert (grid-stride) ----------------
__global__ void f2b(const float* __restrict__ src, __hip_bfloat16* __restrict__ dst, int n) {
  int i = blockIdx.x * blockDim.x + threadIdx.x;
  int stride = gridDim.x * blockDim.x;
  for (; i < n; i += stride) dst[i] = __float2bfloat16(src[i]);
}

__global__ void zerou(unsigned* p, int n) {
  int i = threadIdx.x;
  if (i < n) p[i] = 0u;
}

// ---------------- bf16 GEMM (phased, halved): C[2048][3072] ----------------
__global__ __launch_bounds__(256) void gemm_bias_bt(
    const __hip_bfloat16* __restrict__ A,
    const __hip_bfloat16* __restrict__ Bw,
    const float* __restrict__ bias,
    float* __restrict__ C,
    int rowBase0, int rowBase1) {
  __shared__ short As[128 * 32];
  __shared__ short Bs[128 * 32];
  const int tid = threadIdx.x;
  const int lane = tid & 63;
  const int wid = tid >> 6;
  const int m0 = blockIdx.x * 128;
  const int n0 = blockIdx.y * 128;
  const int grow = (m0 < 1024) ? (rowBase0 + m0) : (rowBase1 + (m0 - 1024));
  const int cb = (m0 < 1024) ? 0 : 3072;
  const int wm = wid & 1, wn = wid >> 1;

  f32x4 acc[4][4] = {};

  const short* Ag = (const short*)A;
  const short* Bg = (const short*)Bw + (size_t)cb * 2048;
  const int srow = wid * 16 + (lane >> 2);
  const int sk = (lane & 3) * 8;

  for (int kb = 0; kb < 2048; kb += 32) {
    async16(Ag + (size_t)(grow + srow) * 2048 + kb + sk, &As[wid * 512]);
    async16(Ag + (size_t)(grow + srow + 64) * 2048 + kb + sk, &As[wid * 512 + 2048]);
    async16(Bg + (size_t)(n0 + srow) * 2048 + kb + sk, &Bs[wid * 512]);
    async16(Bg + (size_t)(n0 + srow + 64) * 2048 + kb + sk, &Bs[wid * 512 + 2048]);
    __syncthreads();

    const int q = (lane >> 4) * 8;
    const int rl = lane & 15;
    short8 a[4], b[4];
#pragma unroll
    for (int i = 0; i < 4; i++) a[i] = *(const short8*)&As[(wm * 64 + i * 16 + rl) * 32 + q];
#pragma unroll
    for (int j = 0; j < 4; j++) b[j] = *(const short8*)&Bs[(wn * 64 + j * 16 + rl) * 32 + q];
#pragma unroll
    for (int i = 0; i < 4; i++)
#pragma unroll
      for (int j = 0; j < 4; j++)
        acc[i][j] = __builtin_amdgcn_mfma_f32_16x16x32_bf16(a[i], b[j], acc[i][j], 0, 0, 0);
    __syncthreads();
  }

  const int rl = lane & 15;
  const int rq = lane >> 4;
#pragma unroll
  for (int i = 0; i < 4; i++) {
#pragma unroll
    for (int j = 0; j < 4; j++) {
      int col = n0 + wn * 64 + j * 16 + rl;
      float bv = bias[cb + col];
#pragma unroll
      for (int r = 0; r < 4; r++) {
        int row = m0 + wm * 64 + i * 16 + rq * 4 + r;
        C[(size_t)row * 3072 + col] = acc[i][j][r] + bv;
      }
    }
  }
}

// ---------------- phase kernel: 16 GRU steps, 1 launch ----------------
// Grid 256 blocks x 512 thr. block = (mh:2)*128 + (d:2)*64 + (ct:64).
// 8 waves = (kq:4 K-quarters) x (mts:2 16-row batch tiles).
// W_hh slice register-resident; fp32 h carried in-register across steps.
// h exchange via MALL-coherent (sc0 sc1) ops; barrier has NO fences:
// __syncthreads' mandatory vmcnt(0) drain pushes each wave's sc1 h-stores
// to the MALL before thread 0's relaxed arrival add.
__global__ __launch_bounds__(512, 2) void gru_phase(
    const __hip_bfloat16* __restrict__ Whhb,  // [6144][1024] bf16
    const float* __restrict__ bhh,            // [6144]
    const float* __restrict__ GX,             // [2048][3072]
    __hip_bfloat16* __restrict__ HB,          // [2][2][64][1024] bf16 double buffer
    float* __restrict__ HF,                   // [2][64][1024] fp32 (phase boundary)
    const float* __restrict__ hfin,           // fp32 h at phase start (h0 or HF)
    __hip_bfloat16* __restrict__ Y,           // [256][64][2048]
    float* __restrict__ outF,                 // [2][64][1024] (final h_n slice)
    unsigned* __restrict__ bar,               // [2 counters, 256B apart]
    int ph, int writeY, int syncbase) {
  __shared__ float P[2][4][3][16][17];

  const int bid = blockIdx.x;
  const int mh = bid >> 7;
  const int d = (bid >> 6) & 1;
  const int ct = bid & 63;
  const int lane = threadIdx.x & 63;
  const int wid = threadIdx.x >> 6;
  const int kq = wid >> 1;   // K-quarter: [kq*256, kq*256+256)
  const int mts = wid & 1;
  const int mt = mh * 2 + mts;
  const int rl = lane & 15;
  const int rq = lane >> 4;

  unsigned* mybar = bar + d * 64;  // per-direction counter, 256B apart

  // ---- register-resident weights: 16 cols x 256 K x 3 gates = 24 short8 ----
  const short* wbase = (const short*)Whhb + (size_t)(d * 3072 + ct * 16 + rl) * 1024 + kq * 256 + rq * 8;
  short8 wB[3][8];
#pragma unroll
  for (int g = 0; g < 3; ++g)
#pragma unroll
    for (int ki = 0; ki < 8; ++ki)
      wB[g][ki] = *(const short8*)&wbase[g * 1048576 + ki * 32];
#pragma unroll
  for (int g = 0; g < 3; ++g)
#pragma unroll
    for (int ki = 0; ki < 8; ++ki)
      keep8(wB[g][ki]);   // pin: forbid remat-from-memory across barrier clobbers

  // ---- per-lane epilogue assignment: (b, c) fixed for all 16 steps ----
  const int c = ct * 16 + rl;
  float bR = bhh[d * 3072 + c];
  float bZ = bhh[d * 3072 + 1024 + c];
  float bN = bhh[d * 3072 + 2048 + c];
  keepf(bR); keepf(bZ); keepf(bN);
  const int b = mt * 16 + kq * 4 + rq;
  const int hoff = d * 65536 + b * 1024 + c;
  float hp = hfin[hoff];  // fp32 h carried in-register across steps

  const int aoff = d * 65536 + (mt * 16 + rl) * 1024 + kq * 256 + rq * 8;

  // preload GX for u=0 (h-independent)
  float gxr, gxz, gxn;
  {
    const int gxB0 = d ? (1024 + 15 * 64) : 0;
    const float* gp0 = GX + (size_t)(gxB0 + b) * 3072 + c;
    gxr = gp0[0]; gxz = gp0[1024]; gxn = gp0[2048];
  }

#pragma unroll 1
  for (int u = 0; u < 16; ++u) {
    if (u) {
      // fence-free barrier: syncthreads drains each wave's sc1 h-stores
      __syncthreads();
      if (threadIdx.x == 0) {
        __hip_atomic_fetch_add(mybar, 1u, __ATOMIC_RELAXED, __HIP_MEMORY_SCOPE_AGENT);
        const unsigned target = (unsigned)(syncbase + u) * 128u;
        int guard = 1 << 18;
        while (__hip_atomic_load(mybar, __ATOMIC_RELAXED, __HIP_MEMORY_SCOPE_AGENT) < target &&
               --guard) {
          __builtin_amdgcn_s_sleep(2);
        }
      }
      __syncthreads();
    }
    const int t = ph * 16 + u;

    // prefetch next step's GX (issued before any barrier clobber of iter u+1;
    // compiler cannot sink loads across the asm memory clobbers)
    float ngxr = 0.f, ngxz = 0.f, ngxn = 0.f;
    if (u < 15) {
      const int nb = d ? (1024 + (14 - u) * 64) : ((u + 1) * 64);
      const float* np = GX + (size_t)(nb + b) * 3072 + c;
      ngxr = np[0]; ngxz = np[1024]; ngxn = np[2048];
    }

    // A-operand: bf16 h via MALL-coherent loads
    const short* hrow = (const short*)HB + (t & 1) * 131072 + aoff;
    short8 av[8];
    load_h8_coherent(hrow, av);

    f32x4 aR = {}, aZ = {}, aN = {};
#pragma unroll
    for (int ki = 0; ki < 8; ++ki) {
      aR = __builtin_amdgcn_mfma_f32_16x16x32_bf16(av[ki], wB[0][ki], aR, 0, 0, 0);
      aZ = __builtin_amdgcn_mfma_f32_16x16x32_bf16(av[ki], wB[1][ki], aZ, 0, 0, 0);
      aN = __builtin_amdgcn_mfma_f32_16x16x32_bf16(av[ki], wB[2][ki], aN, 0, 0, 0);
    }

    // 4-way K reduce through LDS
#pragma unroll
    for (int r = 0; r < 4; ++r) {
      P[mts][kq][0][rq * 4 + r][rl] = aR[r];
      P[mts][kq][1][rq * 4 + r][rl] = aZ[r];
      P[mts][kq][2][rq * 4 + r][rl] = aN[r];
    }
    __syncthreads();

    const int row = kq * 4 + rq;
    const float ghR = P[mts][0][0][row][rl] + P[mts][1][0][row][rl] +
                      P[mts][2][0][row][rl] + P[mts][3][0][row][rl] + bR;
    const float ghZ = P[mts][0][1][row][rl] + P[mts][1][1][row][rl] +
                      P[mts][2][1][row][rl] + P[mts][3][1][row][rl] + bZ;
    const float ghN = P[mts][0][2][row][rl] + P[mts][1][2][row][rl] +
                      P[mts][2][2][row][rl] + P[mts][3][2][row][rl] + bN;

    const float rg = 1.f / (1.f + __expf(-(gxr + ghR)));
    const float zg = 1.f / (1.f + __expf(-(gxz + ghZ)));
    const float nv = gxn + rg * ghN;
    const float ax = fabsf(nv);
    const float e = __expf(-2.f * ax);
    float th = (1.f - e) / (1.f + e);
    th = copysignf(th, nv);
    const float hn = th + zg * (hp - th);
    hp = hn;

    // MALL-coherent h store (write-through; drained by next barrier's vmcnt(0))
    union { __hip_bfloat16 bf; unsigned short us; } cv;
    cv.bf = __float2bfloat16(hn);
    store_h_coherent((__hip_bfloat16*)HB + ((t + 1) & 1) * 131072 + hoff,
                     (unsigned int)cv.us);
    if (writeY) Y[(size_t)((d ? 255 - t : t) * 64 + b) * 2048 + d * 1024 + c] = cv.bf;
    if (u == 15) {
      HF[hoff] = hn;                   // fp32 h for next phase's init
      if (t == 255) outF[hoff] = hn;   // final h_n
    }

    gxr = ngxr; gxz = ngxz; gxn = ngxn;
  }
}

// ---------------- launch ----------------
extern "C" void kernel_launch(void* const* d_in, const int* in_sizes, int n_in,
                              void* d_out, int out_size, void* d_ws, size_t ws_size,
                              hipStream_t stream) {
  (void)in_sizes; (void)n_in; (void)out_size; (void)ws_size;
  const float* x    = (const float*)d_in[0];
  const float* h0   = (const float*)d_in[1];
  const float* w_ih = (const float*)d_in[2];
  const float* w_hh = (const float*)d_in[3];
  const float* b_ih = (const float*)d_in[4];
  const float* b_hh = (const float*)d_in[5];
  float* out = (float*)d_out;

  char* p = (char*)d_ws;
  __hip_bfloat16* SEQA = (__hip_bfloat16*)p; p += (size_t)16384 * 2048 * 2;   // 64 MiB
  __hip_bfloat16* SEQB = (__hip_bfloat16*)p; p += (size_t)16384 * 2048 * 2;   // 64 MiB
  float* GX            = (float*)p;          p += (size_t)2048 * 3072 * 4;    // 24 MiB
  __hip_bfloat16* Wihb = (__hip_bfloat16*)p; p += (size_t)6144 * 2048 * 2;    // 24 MiB
  __hip_bfloat16* Whhb = (__hip_bfloat16*)p; p += (size_t)6144 * 1024 * 2;    // 12 MiB
  __hip_bfloat16* HB   = (__hip_bfloat16*)p; p += (size_t)2 * 131072 * 2;     // 512 KiB
  float* HF            = (float*)p;          p += (size_t)2 * 131072 * 4;     // 1 MiB
  unsigned* BAR        = (unsigned*)p;       p += 1024;

  zerou<<<1, 256, 0, stream>>>(BAR, 128);
  f2b<<<2048, 256, 0, stream>>>(x, SEQA, 16384 * 2048);

  int syncbase = 0;
  for (int l = 0; l < 3; ++l) {
    const __hip_bfloat16* In = (l & 1) ? SEQB : SEQA;
    __hip_bfloat16* Yout = (l & 1) ? SEQA : SEQB;   // unused for l==2
    const int writeY = (l < 2) ? 1 : 0;

    f2b<<<2048, 256, 0, stream>>>(w_ih + (size_t)l * 6144 * 2048, Wihb, 6144 * 2048);
    f2b<<<2048, 256, 0, stream>>>(w_hh + (size_t)l * 6144 * 1024, Whhb, 6144 * 1024);
    f2b<<<64, 256, 0, stream>>>(h0 + (size_t)l * 131072, HB, 131072);

    for (int ph = 0; ph < 16; ++ph) {
      const int rowBase0 = ph * 1024;            // fwd t in [16p, 16p+16)
      const int rowBase1 = 15360 - ph * 1024;    // bwd tau in [240-16p, 256-16p)
      gemm_bias_bt<<<dim3(16, 24), 256, 0, stream>>>(
          In, Wihb, b_ih + l * 6144, GX, rowBase0, rowBase1);

      const float* hfin = (ph == 0) ? (h0 + (size_t)l * 131072) : HF;
      gru_phase<<<256, 512, 0, stream>>>(
          Whhb, b_hh + l * 6144, GX, HB, HF, hfin, Yout,
          out + (size_t)l * 131072, BAR, ph, writeY, syncbase);
      syncbase += 15;   // 15 grid syncs per phase launch
    }
  }
}